// Round 21
// baseline (77.739 us; speedup 1.0000x reference)
//
#include <hip/hip_runtime.h>
#include <hip/hip_bf16.h>

#define N_NODES 20000
#define N_EDGES 320000
#define DATA_DIM 64
#define H 128
#define NVT (N_NODES / 16)   // 1250 node tiles
#define NREP 64              // ssum replicas (atomic contention divider)

// k_pre block ranges
#define DSW_END   (65536 + N_NODES * 32)          // 705536
#define DEG_END   (DSW_END + N_NODES)             // 725536
#define SWZ_BLOCKS ((DEG_END + 255) / 256)        // 2835
#define PRE_BLOCKS (SWZ_BLOCKS + DATA_DIM + 1)    // +65

#define XAB_BLOCKS ((NVT * 2 + 3) / 4)            // 625

typedef __attribute__((ext_vector_type(8))) short bf16x8;
typedef __attribute__((ext_vector_type(4))) float f32x4;

__device__ __forceinline__ unsigned f2bbits(float x) { // fp32 -> bf16 bits (RNE)
    unsigned u = __float_as_uint(x);
    return (u + 0x7FFFu + ((u >> 16) & 1u)) >> 16;
}
__device__ __forceinline__ float blo(unsigned u) { return __uint_as_float(u << 16); }
__device__ __forceinline__ float bhi(unsigned u) { return __uint_as_float(u & 0xffff0000u); }
__device__ __forceinline__ float ftanh(float x) { // ~8 VALU vs libm ~25
    float cx = fminf(fmaxf(x, -9.f), 9.f);
    float e = __expf(2.f * cx);
    return (e - 1.f) / (e + 1.f);
}

// ---------- mega-precompute: weight/data swizzles + Wfsw + r/c/bx + degi/hcnt/ssum zero ----------
// slot map (cancels between A and B operands in MFMA): k = kt*32+(lane>>4)*8+j, m/n = lane&15
__global__ void k_pre(const float* __restrict__ W_emb, const float* __restrict__ W_upd,
                      const float* __restrict__ b_emb, const float* __restrict__ b_msg,
                      const float* __restrict__ W_msg, const float* __restrict__ data,
                      unsigned short* __restrict__ Wfsw,
                      float* __restrict__ r, float* __restrict__ c, float* __restrict__ bx,
                      unsigned short* __restrict__ Wmsw, unsigned short* __restrict__ Wusw,
                      unsigned int* __restrict__ data_sw, int* __restrict__ deg,
                      float* __restrict__ ssum, int* __restrict__ hcnt) {
    int tid = threadIdx.x;
    __shared__ float sh[H];
    if (blockIdx.x >= SWZ_BLOCKS) {
        int d = blockIdx.x - SWZ_BLOCKS;
        int j = tid & 127;
        bool lo = tid < 128;
        if (d < DATA_DIM) {
            if (lo) sh[j] = W_emb[d * H + j];
            __syncthreads();
            if (lo) {
                float acc = 0.f;
                for (int k = 0; k < H; k++)
                    acc += sh[k] * W_upd[(256 + k) * H + j];
                int kt = d >> 5, lane2 = ((d >> 3) & 3) * 16 + (j & 15), jj = d & 7;
                Wfsw[(((kt * 8 + (j >> 4)) * 64 + lane2) << 3) + jj] =
                    (unsigned short)f2bbits(acc);
            }
        } else {
            if (tid == 0) hcnt[0] = 0;
            if (lo) {
                float rj = fmaxf(b_msg[j], 0.f);
                r[j] = rj;
                sh[j] = rj;
                #pragma unroll
                for (int q = 0; q < NREP; q++)
                    ssum[q * H + j] = 0.f;
            }
            __syncthreads();
            if (lo) {
                float cj = 0.f, bxj = 0.f;
                for (int k = 0; k < H; k++) {
                    cj  += sh[k] * W_upd[k * H + j];            // Wu_m rows 0..127
                    bxj += b_emb[k] * W_upd[(256 + k) * H + j]; // Wu_x rows 256..383
                }
                c[j] = cj;
                bx[j] = bxj;
            }
        }
        return;
    }
    int gid = blockIdx.x * 256 + tid;
    if (gid < 32768) {
        int k = gid >> 8, n = gid & 255;
        float src = (n < 128) ? W_msg[k * H + n] : W_msg[(128 + k) * H + (n - 128)];
        int kt = k >> 5, nt = n >> 4;
        int lane = ((k >> 3) & 3) * 16 + (n & 15), j = k & 7;
        Wmsw[(((kt * 16 + nt) * 64 + lane) << 3) + j] = (unsigned short)f2bbits(src);
    } else if (gid < 65536) {
        int id2 = gid - 32768;
        int k = id2 >> 7, n = id2 & 127;
        float src = W_upd[k * H + n];
        int kt = k >> 5, nt = n >> 4;
        int lane = ((k >> 3) & 3) * 16 + (n & 15), j = k & 7;
        Wusw[(((kt * 8 + nt) * 64 + lane) << 3) + j] = (unsigned short)f2bbits(src);
    } else if (gid < DSW_END) {
        int id = gid - 65536;            // [0, N_NODES*32)
        int v = id >> 5, k = (id & 31) * 2;
        float2 dv = *(const float2*)(data + v * DATA_DIM + k);
        int vt = v >> 4, rr = v & 15;
        int kt = k >> 5;
        int lane2 = ((k >> 3) & 3) * 16 + rr, j = k & 7;
        data_sw[(((vt * 2 + kt) * 64 + lane2) << 2) + (j >> 1)] =
            f2bbits(dv.x) | (f2bbits(dv.y) << 16);
    } else if (gid < DEG_END) {
        deg[gid - DSW_END] = 0;
    }
}

// ---------- fused degree-count + bucket scatter: one pass over edges ----------
__global__ void k_sg(const int* __restrict__ dst, const int* __restrict__ src,
                     int* __restrict__ degi, int* __restrict__ srcp2d) {
    int e = blockIdx.x * 256 + threadIdx.x;
    if (e < N_EDGES) {
        int d = dst[e];
        int p = atomicAdd(&degi[d], 1);
        if (p < 64) srcp2d[(d << 6) + p] = src[e];
    }
}

// ---------- fused MFMA: h1 tile (wave-private LDS + h1sw) then [A'|Bb] half ----------
__global__ void __launch_bounds__(256) k_xab(
        const unsigned short* __restrict__ data_sw,
        const unsigned short* __restrict__ Wfsw,
        const float* __restrict__ bx, const int* __restrict__ degi,
        const float* __restrict__ c, const float* __restrict__ b_upd,
        const unsigned short* __restrict__ Wmsw, const float* __restrict__ b_msg,
        unsigned short* __restrict__ h1sw,
        unsigned short* __restrict__ Ab, unsigned short* __restrict__ Bb) {
    __shared__ unsigned short stage[4][4 * 64 * 8]; // 16 KB
    int tid = threadIdx.x;
    int lane = tid & 63, w = tid >> 6;
    int gid = blockIdx.x * 4 + w;  // 0..2499
    int vt = gid >> 1, h = gid & 1;
    if (vt >= NVT) return;
    int col = lane & 15, rg = lane >> 4;
    int v0 = vt * 16;
    // ---- phase 1: h1 tile ----
    {
        f32x4 acc[8];
        #pragma unroll
        for (int i = 0; i < 8; i++) acc[i] = (f32x4){0.f, 0.f, 0.f, 0.f};
        #pragma unroll
        for (int kt = 0; kt < 2; kt++) {
            bf16x8 af = *(const bf16x8*)(data_sw + (((vt * 2 + kt) * 64 + lane) << 3));
            #pragma unroll
            for (int nt = 0; nt < 8; nt++) {
                bf16x8 bfg = *(const bf16x8*)(Wfsw + (((kt * 8 + nt) * 64 + lane) << 3));
                acc[nt] = __builtin_amdgcn_mfma_f32_16x16x32_bf16(af, bfg, acc[nt], 0, 0, 0);
            }
        }
        float dvv[4];
        #pragma unroll
        for (int i = 0; i < 4; i++)
            dvv[i] = (float)degi[v0 + rg * 4 + i];
        #pragma unroll
        for (int nt = 0; nt < 8; nt++) {
            int n = nt * 16 + col;
            float bxn = bx[n], cn = c[n], bun = b_upd[n];
            int kt2 = n >> 5, lane2b = ((n >> 3) & 3) * 16, j2 = n & 7;
            #pragma unroll
            for (int i = 0; i < 4; i++) {
                int rr = rg * 4 + i;
                float hh = ftanh(dvv[i] * cn + acc[nt][i] + bxn + bun);
                stage[w][((kt2 * 64 + lane2b + rr) << 3) + j2] =
                    (unsigned short)f2bbits(hh);
            }
        }
    }
    if (h == 0) {
        #pragma unroll
        for (int kt = 0; kt < 4; kt++) {
            uint4 q = *(const uint4*)&stage[w][(kt * 64 + lane) << 3];
            *(uint4*)(h1sw + ((((size_t)vt * 4 + kt) * 64 + lane) << 3)) = q;
        }
    }
    // ---- phase 2: half-GEMM ----
    f32x4 acc2[8];
    #pragma unroll
    for (int i = 0; i < 8; i++) acc2[i] = (f32x4){0.f, 0.f, 0.f, 0.f};
    #pragma unroll
    for (int kt = 0; kt < 4; kt++) {
        bf16x8 af = *(const bf16x8*)&stage[w][(kt * 64 + lane) << 3];
        #pragma unroll
        for (int nt = 0; nt < 8; nt++) {
            bf16x8 bfg = *(const bf16x8*)(Wmsw + (((kt * 16 + h * 8 + nt) * 64 + lane) << 3));
            acc2[nt] = __builtin_amdgcn_mfma_f32_16x16x32_bf16(af, bfg, acc2[nt], 0, 0, 0);
        }
    }
    int vr = v0 + rg * 4;
    if (h == 0) {
        #pragma unroll
        for (int nt = 0; nt < 8; nt++) {
            int n = nt * 16 + col;
            float bm = b_msg[n];
            #pragma unroll
            for (int i = 0; i < 4; i++)
                Ab[(vr + i) * H + n] = (unsigned short)f2bbits(acc2[nt][i] + bm);
        }
    } else {
        #pragma unroll
        for (int nt = 0; nt < 8; nt++) {
            int n = nt * 16 + col;
            #pragma unroll
            for (int i = 0; i < 4; i++)
                Bb[(vr + i) * H + n] = (unsigned short)f2bbits(acc2[nt][i]);
        }
    }
}

// ---------- fused: edge reduce (16 waves) + h2 MFMA (8 waves) + replicated atomic ssum
//            + LAST-block readout (no threadfence: vmcnt-ordered device atomics) ----------
__global__ void __launch_bounds__(1024) k_eh2(
        const int* __restrict__ degi, const int* __restrict__ srcp2d,
        const unsigned short* __restrict__ Ab, const unsigned short* __restrict__ Bb,
        const float* __restrict__ r,
        const unsigned short* __restrict__ h1sw,
        const unsigned short* __restrict__ data_sw,
        const unsigned short* __restrict__ Wusw,
        const unsigned short* __restrict__ Wfsw,
        const float* __restrict__ bx, const float* __restrict__ b_upd,
        float* __restrict__ ssum, int* __restrict__ hcnt,
        const float* __restrict__ W_ro, const float* __restrict__ b_ro,
        float* __restrict__ out) {
    __shared__ unsigned int m2l[1024]; // 4 KB: 16x128 m2 tile, fragment layout
    __shared__ int lastFlag;
    __shared__ float ss[H];
    __shared__ float red[8][H];
    int tid = threadIdx.x;
    int lane = tid & 63, w = tid >> 6;   // 16 waves
    int vt = blockIdx.x;
    int v0 = vt * 16;
    // ---- edge phase: wave w owns node v0+w ----
    {
        int v = v0 + w;
        int cc = lane & 31, half = lane >> 5;
        uint2 au = *(const uint2*)(Ab + (size_t)v * H + 4 * cc);
        float t0 = blo(au.x), t1 = bhi(au.x), t2 = blo(au.y), t3 = bhi(au.y);
        float4 rv = *(const float4*)(r + 4 * cc);
        int dvi = degi[v];
        int cnt = min(dvi, 64);
        float dv = (float)dvi;
        int sv = srcp2d[(v << 6) + lane];  // lanes >= cnt never consumed
        float a0 = 0.f, a1 = 0.f, a2 = 0.f, a3 = 0.f;
        // masked 16-edge blocks: always 8 independent loads in flight.
        for (int i = 0; i < cnt; i += 16) {
            uint2 u[8];
            bool p[8];
            #pragma unroll
            for (int j = 0; j < 8; j++) {
                int ie = i + 2 * j;
                int se = __builtin_amdgcn_readlane(sv, ie);
                int so = __builtin_amdgcn_readlane(sv, ie + 1);
                bool me = ie < cnt, mo = (ie + 1) < cnt;
                bool pm = half ? mo : me;
                int s = pm ? (half ? so : se) : 0;  // dummy -> row 0 (L1-hot)
                p[j] = pm;
                u[j] = *(const uint2*)(Bb + (size_t)s * H + 4 * cc);
            }
            #pragma unroll
            for (int j = 0; j < 8; j++) {
                a0 += p[j] ? fmaxf(t0 + blo(u[j].x), 0.f) : 0.f;
                a1 += p[j] ? fmaxf(t1 + bhi(u[j].x), 0.f) : 0.f;
                a2 += p[j] ? fmaxf(t2 + blo(u[j].y), 0.f) : 0.f;
                a3 += p[j] ? fmaxf(t3 + bhi(u[j].y), 0.f) : 0.f;
            }
        }
        a0 += __shfl_xor(a0, 32);
        a1 += __shfl_xor(a1, 32);
        a2 += __shfl_xor(a2, 32);
        a3 += __shfl_xor(a3, 32);
        if (half == 0) {
            a0 += dv * rv.x; a1 += dv * rv.y; a2 += dv * rv.z; a3 += dv * rv.w;
            int rr = w;  // node index within tile
            int sbase = (((cc >> 3) * 64 + ((cc >> 1) & 3) * 16 + rr) << 3)
                        + (cc & 1) * 4;
            unsigned int* p2 = m2l + (sbase >> 1);
            p2[0] = f2bbits(a0) | (f2bbits(a1) << 16);
            p2[1] = f2bbits(a2) | (f2bbits(a3) << 16);
        }
    }
    __syncthreads();
    // ---- h2 MFMA phase: waves 0-7, ONE n-tile each; K=320 ----
    if (w < 8) {
        f32x4 acc = (f32x4){0.f, 0.f, 0.f, 0.f};
        #pragma unroll
        for (int kt = 0; kt < 8; kt++) {
            bf16x8 af;
            if (kt < 4)
                af = *(const bf16x8*)((const unsigned short*)m2l + ((kt * 64 + lane) << 3));
            else
                af = *(const bf16x8*)(h1sw + ((((size_t)vt * 4 + (kt - 4)) * 64 + lane) << 3));
            bf16x8 bfg = *(const bf16x8*)(Wusw + (((kt * 8 + w) * 64 + lane) << 3));
            acc = __builtin_amdgcn_mfma_f32_16x16x32_bf16(af, bfg, acc, 0, 0, 0);
        }
        #pragma unroll
        for (int kt = 0; kt < 2; kt++) {
            bf16x8 af = *(const bf16x8*)(data_sw + ((((size_t)vt * 2 + kt) * 64 + lane) << 3));
            bf16x8 bfg = *(const bf16x8*)(Wfsw + (((kt * 8 + w) * 64 + lane) << 3));
            acc = __builtin_amdgcn_mfma_f32_16x16x32_bf16(af, bfg, acc, 0, 0, 0);
        }
        int col = lane & 15, rg = lane >> 4;
        int n = w * 16 + col;
        float bias = bx[n] + b_upd[n];
        float s = 0.f;
        #pragma unroll
        for (int i = 0; i < 4; i++)
            s += ftanh(acc[i] + bias);
        s += __shfl_xor(s, 16);
        s += __shfl_xor(s, 32);
        if (rg == 0) {
            // device-scope atomic with return: consuming `old` forces vmcnt wait,
            // so the add has completed at the coherent point before the barrier.
            float old = atomicAdd(&ssum[(vt & (NREP - 1)) * H + n], s);
            asm volatile("" :: "v"(old));
        }
    }
    __syncthreads();
    if (tid == 0) {
        int old = atomicAdd(hcnt, 1);
        lastFlag = (old == NVT - 1);
    }
    __syncthreads();
    if (!lastFlag) return;
    // ---- last block: out = relu((sum replicas) @ W_ro + b_ro) ----
    int j = tid & 127, g = tid >> 7; // 8 groups
    float pr = 0.f;
    #pragma unroll
    for (int q = 0; q < NREP / 8; q++)
        pr += atomicAdd(&ssum[(g + q * 8) * H + j], 0.f); // coherent read
    red[g][j] = pr;
    __syncthreads();
    if (tid < H) {
        float tot = 0.f;
        #pragma unroll
        for (int q = 0; q < 8; q++)
            tot += red[q][tid];
        ss[tid] = tot;
    }
    __syncthreads();
    float s2 = 0.f;
    #pragma unroll
    for (int q = 0; q < 16; q++) {
        int k = g * 16 + q;
        s2 += ss[k] * W_ro[k * H + j];
    }
    red[g][j] = s2;
    __syncthreads();
    if (tid < H) {
        float acc = b_ro[tid];
        #pragma unroll
        for (int q = 0; q < 8; q++)
            acc += red[q][tid];
        out[tid] = fmaxf(acc, 0.f);
    }
}

extern "C" void kernel_launch(void* const* d_in, const int* in_sizes, int n_in,
                              void* d_out, int out_size, void* d_ws, size_t ws_size,
                              hipStream_t stream) {
    const float* data   = (const float*)d_in[0];
    const int*   esrc   = (const int*)d_in[1];
    const int*   edst   = (const int*)d_in[2];
    const float* W_emb  = (const float*)d_in[3];
    const float* b_emb  = (const float*)d_in[4];
    const float* W_msg  = (const float*)d_in[5];
    const float* b_msg  = (const float*)d_in[6];
    const float* W_upd  = (const float*)d_in[7];
    const float* b_upd  = (const float*)d_in[8];
    const float* W_ro   = (const float*)d_in[9];
    const float* b_ro   = (const float*)d_in[10];
    float* out = (float*)d_out;

    // workspace layout (16B-aligned chunks)
    unsigned short* Ab   = (unsigned short*)d_ws;  // N*H bf16 (linear)
    unsigned short* h1sw = Ab + N_NODES * H;       // N*H bf16 (swizzled)
    unsigned short* Bb   = h1sw + N_NODES * H;     // N*H bf16 (linear)
    unsigned short* dsw  = Bb + N_NODES * H;       // N*DATA_DIM bf16 (swizzled)
    unsigned short* Wmsw = dsw + N_NODES * DATA_DIM; // 32768 bf16
    unsigned short* Wusw = Wmsw + 32768;           // 32768 bf16
    unsigned short* Wfsw = Wusw + 32768;           // 8192 bf16
    float* ssum  = (float*)(Wfsw + 8192);          // NREP*H
    float* r     = ssum + NREP * H;                // H
    float* c     = r + H;                          // H
    float* bx    = c + H;                          // H
    int* hcnt    = (int*)(bx + H);                 // 1 (+pad)
    int* degi    = hcnt + 4;                       // N
    int* srcp2d  = degi + N_NODES;                 // N*64

    k_pre<<<PRE_BLOCKS, 256, 0, stream>>>(W_emb, W_upd, b_emb, b_msg, W_msg, data,
                                          Wfsw, r, c, bx, Wmsw, Wusw,
                                          (unsigned int*)dsw, degi, ssum, hcnt);
    k_sg<<<(N_EDGES + 255) / 256, 256, 0, stream>>>(edst, esrc, degi, srcp2d);
    k_xab<<<XAB_BLOCKS, 256, 0, stream>>>(dsw, Wfsw, bx, degi, c, b_upd,
                                          Wmsw, b_msg, h1sw, Ab, Bb);
    k_eh2<<<NVT, 1024, 0, stream>>>(degi, srcp2d, Ab, Bb, r, h1sw, dsw,
                                    Wusw, Wfsw, bx, b_upd, ssum, hcnt,
                                    W_ro, b_ro, out);
}

// Round 22
// 72.327 us; speedup vs baseline: 1.0748x; 1.0748x over previous
//
#include <hip/hip_runtime.h>
#include <hip/hip_bf16.h>

#define N_NODES 20000
#define N_EDGES 320000
#define DATA_DIM 64
#define H 128
#define NVT (N_NODES / 16)   // 1250 node tiles
#define NREP 64              // ssum replicas (atomic contention divider)

// k_pre block ranges: [0,256) weight swz | [256,335) degi zero | [335,400) prewf
#define WSWZ_BLOCKS 256
#define DEGZ_BLOCKS ((N_NODES + 255) / 256)       // 79
#define PRE_BLOCKS  (WSWZ_BLOCKS + DEGZ_BLOCKS + DATA_DIM + 1) // 400

// k_sx block ranges: [0,1250) scatter | [1250,3750) data swizzle
#define SG_BLOCKS   ((N_EDGES + 255) / 256)       // 1250
#define DSWZ_BLOCKS (N_NODES * 32 / 256)          // 2500
#define SX_BLOCKS   (SG_BLOCKS + DSWZ_BLOCKS)

#define XAB_BLOCKS ((NVT * 2 + 3) / 4)            // 625

typedef __attribute__((ext_vector_type(8))) short bf16x8;
typedef __attribute__((ext_vector_type(4))) float f32x4;

__device__ __forceinline__ unsigned f2bbits(float x) { // fp32 -> bf16 bits (RNE)
    unsigned u = __float_as_uint(x);
    return (u + 0x7FFFu + ((u >> 16) & 1u)) >> 16;
}
__device__ __forceinline__ float blo(unsigned u) { return __uint_as_float(u << 16); }
__device__ __forceinline__ float bhi(unsigned u) { return __uint_as_float(u & 0xffff0000u); }
__device__ __forceinline__ float ftanh(float x) { // ~8 VALU vs libm ~25
    float cx = fminf(fmaxf(x, -9.f), 9.f);
    float e = __expf(2.f * cx);
    return (e - 1.f) / (e + 1.f);
}

// ---------- precompute: weight swizzles + degi zero + Wfsw/r/c/bx + ssum zero ----------
// slot map (cancels between A and B operands in MFMA): k = kt*32+(lane>>4)*8+j, m/n = lane&15
__global__ void k_pre(const float* __restrict__ W_emb, const float* __restrict__ W_upd,
                      const float* __restrict__ b_emb, const float* __restrict__ b_msg,
                      const float* __restrict__ W_msg,
                      unsigned short* __restrict__ Wfsw,
                      float* __restrict__ r, float* __restrict__ c, float* __restrict__ bx,
                      unsigned short* __restrict__ Wmsw, unsigned short* __restrict__ Wusw,
                      int* __restrict__ deg, float* __restrict__ ssum) {
    int tid = threadIdx.x;
    __shared__ float sh[H];
    if (blockIdx.x >= WSWZ_BLOCKS + DEGZ_BLOCKS) {
        // ---- prewf ----
        int d = blockIdx.x - (WSWZ_BLOCKS + DEGZ_BLOCKS);
        int j = tid & 127;
        bool lo = tid < 128;
        if (d < DATA_DIM) {
            if (lo) sh[j] = W_emb[d * H + j];
            __syncthreads();
            if (lo) {
                float acc = 0.f;
                for (int k = 0; k < H; k++)
                    acc += sh[k] * W_upd[(256 + k) * H + j];
                int kt = d >> 5, lane2 = ((d >> 3) & 3) * 16 + (j & 15), jj = d & 7;
                Wfsw[(((kt * 8 + (j >> 4)) * 64 + lane2) << 3) + jj] =
                    (unsigned short)f2bbits(acc);
            }
        } else {
            if (lo) {
                float rj = fmaxf(b_msg[j], 0.f);
                r[j] = rj;
                sh[j] = rj;
                #pragma unroll
                for (int q = 0; q < NREP; q++)
                    ssum[q * H + j] = 0.f;
            }
            __syncthreads();
            if (lo) {
                float cj = 0.f, bxj = 0.f;
                for (int k = 0; k < H; k++) {
                    cj  += sh[k] * W_upd[k * H + j];            // Wu_m rows 0..127
                    bxj += b_emb[k] * W_upd[(256 + k) * H + j]; // Wu_x rows 256..383
                }
                c[j] = cj;
                bx[j] = bxj;
            }
        }
        return;
    }
    if (blockIdx.x >= WSWZ_BLOCKS) {
        int v = (blockIdx.x - WSWZ_BLOCKS) * 256 + tid;
        if (v < N_NODES) deg[v] = 0;
        return;
    }
    int gid = blockIdx.x * 256 + tid;   // [0, 65536)
    if (gid < 32768) {
        int k = gid >> 8, n = gid & 255;
        float src = (n < 128) ? W_msg[k * H + n] : W_msg[(128 + k) * H + (n - 128)];
        int kt = k >> 5, nt = n >> 4;
        int lane = ((k >> 3) & 3) * 16 + (n & 15), j = k & 7;
        Wmsw[(((kt * 16 + nt) * 64 + lane) << 3) + j] = (unsigned short)f2bbits(src);
    } else {
        int id2 = gid - 32768;
        int k = id2 >> 7, n = id2 & 127;
        float src = W_upd[k * H + n];
        int kt = k >> 5, nt = n >> 4;
        int lane = ((k >> 3) & 3) * 16 + (n & 15), j = k & 7;
        Wusw[(((kt * 8 + nt) * 64 + lane) << 3) + j] = (unsigned short)f2bbits(src);
    }
}

// ---------- merged: scatter (latency-bound) || data swizzle (BW-bound) ----------
__global__ void k_sx(const int* __restrict__ dst, const int* __restrict__ src,
                     int* __restrict__ degi, int* __restrict__ srcp2d,
                     const float* __restrict__ data,
                     unsigned int* __restrict__ data_sw) {
    int tid = threadIdx.x;
    if (blockIdx.x < SG_BLOCKS) {
        int e = blockIdx.x * 256 + tid;
        if (e < N_EDGES) {
            int d = dst[e];
            int p = atomicAdd(&degi[d], 1);
            if (p < 64) srcp2d[(d << 6) + p] = src[e];
        }
        return;
    }
    int id = (blockIdx.x - SG_BLOCKS) * 256 + tid;  // [0, N_NODES*32), exact
    int v = id >> 5, k = (id & 31) * 2;
    float2 dv = *(const float2*)(data + v * DATA_DIM + k);
    int vt = v >> 4, rr = v & 15;
    int kt = k >> 5;
    int lane2 = ((k >> 3) & 3) * 16 + rr, j = k & 7;
    data_sw[(((vt * 2 + kt) * 64 + lane2) << 2) + (j >> 1)] =
        f2bbits(dv.x) | (f2bbits(dv.y) << 16);
}

// ---------- fused MFMA: h1 tile (wave-private LDS + h1sw) then [A'|Bb] half ----------
__global__ void __launch_bounds__(256) k_xab(
        const unsigned short* __restrict__ data_sw,
        const unsigned short* __restrict__ Wfsw,
        const float* __restrict__ bx, const int* __restrict__ degi,
        const float* __restrict__ c, const float* __restrict__ b_upd,
        const unsigned short* __restrict__ Wmsw, const float* __restrict__ b_msg,
        unsigned short* __restrict__ h1sw,
        unsigned short* __restrict__ Ab, unsigned short* __restrict__ Bb) {
    __shared__ unsigned short stage[4][4 * 64 * 8]; // 16 KB
    int tid = threadIdx.x;
    int lane = tid & 63, w = tid >> 6;
    int gid = blockIdx.x * 4 + w;  // 0..2499
    int vt = gid >> 1, h = gid & 1;
    if (vt >= NVT) return;
    int col = lane & 15, rg = lane >> 4;
    int v0 = vt * 16;
    // ---- phase 1: h1 tile ----
    {
        f32x4 acc[8];
        #pragma unroll
        for (int i = 0; i < 8; i++) acc[i] = (f32x4){0.f, 0.f, 0.f, 0.f};
        #pragma unroll
        for (int kt = 0; kt < 2; kt++) {
            bf16x8 af = *(const bf16x8*)(data_sw + (((vt * 2 + kt) * 64 + lane) << 3));
            #pragma unroll
            for (int nt = 0; nt < 8; nt++) {
                bf16x8 bfg = *(const bf16x8*)(Wfsw + (((kt * 8 + nt) * 64 + lane) << 3));
                acc[nt] = __builtin_amdgcn_mfma_f32_16x16x32_bf16(af, bfg, acc[nt], 0, 0, 0);
            }
        }
        float dvv[4];
        #pragma unroll
        for (int i = 0; i < 4; i++)
            dvv[i] = (float)degi[v0 + rg * 4 + i];
        #pragma unroll
        for (int nt = 0; nt < 8; nt++) {
            int n = nt * 16 + col;
            float bxn = bx[n], cn = c[n], bun = b_upd[n];
            int kt2 = n >> 5, lane2b = ((n >> 3) & 3) * 16, j2 = n & 7;
            #pragma unroll
            for (int i = 0; i < 4; i++) {
                int rr = rg * 4 + i;
                float hh = ftanh(dvv[i] * cn + acc[nt][i] + bxn + bun);
                stage[w][((kt2 * 64 + lane2b + rr) << 3) + j2] =
                    (unsigned short)f2bbits(hh);
            }
        }
    }
    if (h == 0) {
        #pragma unroll
        for (int kt = 0; kt < 4; kt++) {
            uint4 q = *(const uint4*)&stage[w][(kt * 64 + lane) << 3];
            *(uint4*)(h1sw + ((((size_t)vt * 4 + kt) * 64 + lane) << 3)) = q;
        }
    }
    // ---- phase 2: half-GEMM ----
    f32x4 acc2[8];
    #pragma unroll
    for (int i = 0; i < 8; i++) acc2[i] = (f32x4){0.f, 0.f, 0.f, 0.f};
    #pragma unroll
    for (int kt = 0; kt < 4; kt++) {
        bf16x8 af = *(const bf16x8*)&stage[w][(kt * 64 + lane) << 3];
        #pragma unroll
        for (int nt = 0; nt < 8; nt++) {
            bf16x8 bfg = *(const bf16x8*)(Wmsw + (((kt * 16 + h * 8 + nt) * 64 + lane) << 3));
            acc2[nt] = __builtin_amdgcn_mfma_f32_16x16x32_bf16(af, bfg, acc2[nt], 0, 0, 0);
        }
    }
    int vr = v0 + rg * 4;
    if (h == 0) {
        #pragma unroll
        for (int nt = 0; nt < 8; nt++) {
            int n = nt * 16 + col;
            float bm = b_msg[n];
            #pragma unroll
            for (int i = 0; i < 4; i++)
                Ab[(vr + i) * H + n] = (unsigned short)f2bbits(acc2[nt][i] + bm);
        }
    } else {
        #pragma unroll
        for (int nt = 0; nt < 8; nt++) {
            int n = nt * 16 + col;
            #pragma unroll
            for (int i = 0; i < 4; i++)
                Bb[(vr + i) * H + n] = (unsigned short)f2bbits(acc2[nt][i]);
        }
    }
}

// ---------- fused: edge reduce (16 waves, 1 node/wave, masked 16-edge blocks)
//            then h2 MFMA (8 waves, ONE n-tile each, K=320) + replicated atomic ssum ----------
__global__ void __launch_bounds__(1024) k_eh2(
        const int* __restrict__ degi, const int* __restrict__ srcp2d,
        const unsigned short* __restrict__ Ab, const unsigned short* __restrict__ Bb,
        const float* __restrict__ r,
        const unsigned short* __restrict__ h1sw,
        const unsigned short* __restrict__ data_sw,
        const unsigned short* __restrict__ Wusw,
        const unsigned short* __restrict__ Wfsw,
        const float* __restrict__ bx, const float* __restrict__ b_upd,
        float* __restrict__ ssum) {
    __shared__ unsigned int m2l[1024]; // 4 KB: 16x128 m2 tile, fragment layout
    int tid = threadIdx.x;
    int lane = tid & 63, w = tid >> 6;   // 16 waves
    int vt = blockIdx.x;
    int v0 = vt * 16;
    // ---- edge phase: wave w owns node v0+w ----
    {
        int v = v0 + w;
        int cc = lane & 31, half = lane >> 5;
        uint2 au = *(const uint2*)(Ab + (size_t)v * H + 4 * cc);
        float t0 = blo(au.x), t1 = bhi(au.x), t2 = blo(au.y), t3 = bhi(au.y);
        float4 rv = *(const float4*)(r + 4 * cc);
        int dvi = degi[v];
        int cnt = min(dvi, 64);
        float dv = (float)dvi;
        int sv = srcp2d[(v << 6) + lane];  // lanes >= cnt never consumed
        float a0 = 0.f, a1 = 0.f, a2 = 0.f, a3 = 0.f;
        // masked 16-edge blocks: always 8 independent loads in flight.
        for (int i = 0; i < cnt; i += 16) {
            uint2 u[8];
            bool p[8];
            #pragma unroll
            for (int j = 0; j < 8; j++) {
                int ie = i + 2 * j;
                int se = __builtin_amdgcn_readlane(sv, ie);
                int so = __builtin_amdgcn_readlane(sv, ie + 1);
                bool me = ie < cnt, mo = (ie + 1) < cnt;
                bool pm = half ? mo : me;
                int s = pm ? (half ? so : se) : 0;  // dummy -> row 0 (L1-hot)
                p[j] = pm;
                u[j] = *(const uint2*)(Bb + (size_t)s * H + 4 * cc);
            }
            #pragma unroll
            for (int j = 0; j < 8; j++) {
                a0 += p[j] ? fmaxf(t0 + blo(u[j].x), 0.f) : 0.f;
                a1 += p[j] ? fmaxf(t1 + bhi(u[j].x), 0.f) : 0.f;
                a2 += p[j] ? fmaxf(t2 + blo(u[j].y), 0.f) : 0.f;
                a3 += p[j] ? fmaxf(t3 + bhi(u[j].y), 0.f) : 0.f;
            }
        }
        a0 += __shfl_xor(a0, 32);
        a1 += __shfl_xor(a1, 32);
        a2 += __shfl_xor(a2, 32);
        a3 += __shfl_xor(a3, 32);
        if (half == 0) {
            a0 += dv * rv.x; a1 += dv * rv.y; a2 += dv * rv.z; a3 += dv * rv.w;
            int rr = w;  // node index within tile
            int sbase = (((cc >> 3) * 64 + ((cc >> 1) & 3) * 16 + rr) << 3)
                        + (cc & 1) * 4;
            unsigned int* p2 = m2l + (sbase >> 1);
            p2[0] = f2bbits(a0) | (f2bbits(a1) << 16);
            p2[1] = f2bbits(a2) | (f2bbits(a3) << 16);
        }
    }
    __syncthreads();
    if (w >= 8) return;   // 8 waves for h2, ONE n-tile each (no further barriers)
    // ---- h2 MFMA phase: wave w -> n-tile w; K=320 ----
    f32x4 acc = (f32x4){0.f, 0.f, 0.f, 0.f};
    #pragma unroll
    for (int kt = 0; kt < 8; kt++) {
        bf16x8 af;
        if (kt < 4)
            af = *(const bf16x8*)((const unsigned short*)m2l + ((kt * 64 + lane) << 3));
        else
            af = *(const bf16x8*)(h1sw + ((((size_t)vt * 4 + (kt - 4)) * 64 + lane) << 3));
        bf16x8 bfg = *(const bf16x8*)(Wusw + (((kt * 8 + w) * 64 + lane) << 3));
        acc = __builtin_amdgcn_mfma_f32_16x16x32_bf16(af, bfg, acc, 0, 0, 0);
    }
    #pragma unroll
    for (int kt = 0; kt < 2; kt++) {
        bf16x8 af = *(const bf16x8*)(data_sw + ((((size_t)vt * 2 + kt) * 64 + lane) << 3));
        bf16x8 bfg = *(const bf16x8*)(Wfsw + (((kt * 8 + w) * 64 + lane) << 3));
        acc = __builtin_amdgcn_mfma_f32_16x16x32_bf16(af, bfg, acc, 0, 0, 0);
    }
    int col = lane & 15, rg = lane >> 4;
    int n = w * 16 + col;
    float bias = bx[n] + b_upd[n];
    float s = 0.f;
    #pragma unroll
    for (int i = 0; i < 4; i++)
        s += ftanh(acc[i] + bias);
    s += __shfl_xor(s, 16);
    s += __shfl_xor(s, 32);
    if (rg == 0) atomicAdd(&ssum[(vt & (NREP - 1)) * H + n], s);
}

// ---------- out = relu((sum replicas) @ W_ro + b_ro), k-parallel ----------
__global__ void __launch_bounds__(1024) k_out(
        const float* __restrict__ ssum,
        const float* __restrict__ W_ro, const float* __restrict__ b_ro,
        float* __restrict__ out) {
    __shared__ float ss[H];
    __shared__ float red[8][H]; // 4 KB
    int tid = threadIdx.x;
    int j = tid & 127, g = tid >> 7; // 8 groups
    // reduce NREP replicas: group g handles replicas g, g+8, ...
    float pr = 0.f;
    #pragma unroll
    for (int q = 0; q < NREP / 8; q++)
        pr += ssum[(g + q * 8) * H + j];
    red[g][j] = pr;
    __syncthreads();
    if (tid < H) {
        float tot = 0.f;
        #pragma unroll
        for (int q = 0; q < 8; q++)
            tot += red[q][tid];
        ss[tid] = tot;
    }
    __syncthreads();
    float s = 0.f;
    #pragma unroll
    for (int q = 0; q < 16; q++) {
        int k = g * 16 + q;
        s += ss[k] * W_ro[k * H + j];
    }
    red[g][j] = s;
    __syncthreads();
    if (tid < H) {
        float acc = b_ro[tid];
        #pragma unroll
        for (int q = 0; q < 8; q++)
            acc += red[q][tid];
        out[tid] = fmaxf(acc, 0.f);
    }
}

extern "C" void kernel_launch(void* const* d_in, const int* in_sizes, int n_in,
                              void* d_out, int out_size, void* d_ws, size_t ws_size,
                              hipStream_t stream) {
    const float* data   = (const float*)d_in[0];
    const int*   esrc   = (const int*)d_in[1];
    const int*   edst   = (const int*)d_in[2];
    const float* W_emb  = (const float*)d_in[3];
    const float* b_emb  = (const float*)d_in[4];
    const float* W_msg  = (const float*)d_in[5];
    const float* b_msg  = (const float*)d_in[6];
    const float* W_upd  = (const float*)d_in[7];
    const float* b_upd  = (const float*)d_in[8];
    const float* W_ro   = (const float*)d_in[9];
    const float* b_ro   = (const float*)d_in[10];
    float* out = (float*)d_out;

    // workspace layout (16B-aligned chunks)
    unsigned short* Ab   = (unsigned short*)d_ws;  // N*H bf16 (linear)
    unsigned short* h1sw = Ab + N_NODES * H;       // N*H bf16 (swizzled)
    unsigned short* Bb   = h1sw + N_NODES * H;     // N*H bf16 (linear)
    unsigned short* dsw  = Bb + N_NODES * H;       // N*DATA_DIM bf16 (swizzled)
    unsigned short* Wmsw = dsw + N_NODES * DATA_DIM; // 32768 bf16
    unsigned short* Wusw = Wmsw + 32768;           // 32768 bf16
    unsigned short* Wfsw = Wusw + 32768;           // 8192 bf16
    float* ssum  = (float*)(Wfsw + 8192);          // NREP*H
    float* r     = ssum + NREP * H;                // H
    float* c     = r + H;                          // H
    float* bx    = c + H;                          // H
    int* degi    = (int*)(bx + H);                 // N
    int* srcp2d  = degi + N_NODES;                 // N*64

    k_pre<<<PRE_BLOCKS, 256, 0, stream>>>(W_emb, W_upd, b_emb, b_msg, W_msg,
                                          Wfsw, r, c, bx, Wmsw, Wusw, degi, ssum);
    k_sx<<<SX_BLOCKS, 256, 0, stream>>>(edst, esrc, degi, srcp2d, data,
                                        (unsigned int*)dsw);
    k_xab<<<XAB_BLOCKS, 256, 0, stream>>>(dsw, Wfsw, bx, degi, c, b_upd,
                                          Wmsw, b_msg, h1sw, Ab, Bb);
    k_eh2<<<NVT, 1024, 0, stream>>>(degi, srcp2d, Ab, Bb, r, h1sw, dsw,
                                    Wusw, Wfsw, bx, b_upd, ssum);
    k_out<<<1, 1024, 0, stream>>>(ssum, W_ro, b_ro, out);
}